// Round 2
// baseline (484.774 us; speedup 1.0000x reference)
//
#include <hip/hip_runtime.h>

typedef unsigned short u16;
typedef __attribute__((ext_vector_type(8))) __bf16 bf16x8;
typedef __attribute__((ext_vector_type(4))) float f32x4;
typedef __attribute__((ext_vector_type(8))) u16 u16x8;
typedef __attribute__((ext_vector_type(4))) u16 u16x4;

#define DIMSZ 1024
#define HEADS 16
#define BLKSZ 129
#define NBLK 32
#define NTOK (BLKSZ * NBLK)      // 4128
#define BATCH 4
#define MROWS (BATCH * NTOK)     // 16512

#define MFMA __builtin_amdgcn_mfma_f32_16x16x32_bf16

#define SSTR 152   // S/P LDS row stride (bf16): 2-way bank alias only (free)
#define KSTR 72    // K tile LDS row stride

#define NKT 32     // K tiles of 32: 1024/32

__device__ __forceinline__ float bf2f(u16 u) {
  return __uint_as_float(((unsigned)u) << 16);
}
__device__ __forceinline__ u16 f2bf(float f) {
  unsigned u = __float_as_uint(f);
  u += 0x7FFFu + ((u >> 16) & 1u);   // round-to-nearest-even
  return (u16)(u >> 16);
}

// async global->LDS, 16B/lane; LDS dest = wave-uniform base + lane*16 (m97)
#define GLD16(ldsp, gp) __builtin_amdgcn_global_load_lds( \
    (const __attribute__((address_space(1))) void*)(gp),   \
    (__attribute__((address_space(3))) void*)(ldsp), 16, 0, 0)

// ---------------------------------------------------------------------------
// f32 -> bf16 cast, 4 elems/thread. n multiple of 1024.
// ---------------------------------------------------------------------------
__global__ __launch_bounds__(256) void cast_f32_bf16(
    const float* __restrict__ in, u16* __restrict__ out, int n)
{
  int i = (blockIdx.x * 256 + threadIdx.x) * 4;
  if (i < n) {
    float4 f = *(const float4*)(in + i);
    u16x4 o = { f2bf(f.x), f2bf(f.y), f2bf(f.z), f2bf(f.w) };
    *(u16x4*)(out + i) = o;
  }
}

// ---------------------------------------------------------------------------
// Bijective XCD-aware block swizzle (m204): contiguous logical chunk per XCD.
// ---------------------------------------------------------------------------
__device__ __forceinline__ int xcd_swz(int bid, int nwg) {
  const int xcd = bid & 7, l = bid >> 3;
  const int q = nwg >> 3, r = nwg & 7;
  return (xcd < r ? xcd * (q + 1) : r * (q + 1) + (xcd - r) * q) + l;
}

// ---------------------------------------------------------------------------
// Stage one BK=32 slot (A 256x32 = 16KB + B 256x32 = 16KB) into the ring.
// 4 x global_load_lds dwordx4 per thread; LDS dest linear (lane*16 rule).
// Source cols pre-swizzled (chunk ^= (row>>1)&3) so a swizzled ds_read sees
// bank-uniform data (rule #21: swizzle source+read, keep DMA dest linear).
// ---------------------------------------------------------------------------
__device__ __forceinline__ void stage_slot(u16* slot, const u16* gA,
                                           const u16* gB, int tid) {
  GLD16(slot + tid * 8, gA);                       // A rows 0..127
  GLD16(slot + 4096 + tid * 8, gA + 128 * DIMSZ);  // A rows 128..255
  GLD16(slot + 8192 + tid * 8, gB);                // B rows 0..127
  GLD16(slot + 12288 + tid * 8, gB + 128 * DIMSZ); // B rows 128..255
}

// ---------------------------------------------------------------------------
// Pipelined GEMM mainloop: BM=256 x BN=256, BK=32, 8 waves (2M x 4N),
// per-wave output 128x64 (acc[8][4]) -> 42.7 MFMA-FLOP per LDS-read-byte,
// 33% more fragment reuse than 64x64/wave. 4-slot LDS ring (128 KB).
// Counted vmcnt(4) + raw s_barrier: slot t+2's 4 loads stay in flight
// across the barrier; slot t+2 was last read at iter t-2 (>=1 barrier ago).
// XOR swizzle (chunk ^ (row>>1)&3) makes the b128 reads 2-way max (free).
// ---------------------------------------------------------------------------
__device__ __forceinline__ void gemm_pipe256(
    const u16* __restrict__ A, const u16* __restrict__ Bm,
    int m0, int n0, int tid, u16 (*sm)[16384], f32x4 (*acc)[4])
{
  const int lane = tid & 63, w = tid >> 6;
  const int qd = lane >> 4, l15 = lane & 15;
  const int wm = (w >> 2) * 128, wn = (w & 3) * 64;
  // read-side swizzle: chunk qd ^ ((row>>1)&3); row bits below 16 come from
  // l15 only (wm,wn,mi*16,ni*16 are 16-aligned) -> lane-constant.
  const int qdsw = (qd ^ ((l15 >> 1) & 3)) * 8;

  // staging: thread covers row tid>>2 (+128), 16B chunk tid&3, swizzled src
  const int srow = tid >> 2;
  const int schk = (tid & 3) ^ ((tid >> 3) & 3);
  const u16* gA = A + (size_t)(m0 + srow) * DIMSZ + schk * 8;
  const u16* gB = Bm + (size_t)(n0 + srow) * DIMSZ + schk * 8;

  // prologue: stage slots 0,1; land slot 0, keep slot 1's 4 loads in flight
  stage_slot(sm[0], gA, gB, tid);
  stage_slot(sm[1], gA + 32, gB + 32, tid);
  asm volatile("s_waitcnt vmcnt(4)" ::: "memory");
  __builtin_amdgcn_s_barrier();
  __builtin_amdgcn_sched_barrier(0);

#pragma unroll 4
  for (int t = 0; t < NKT; ++t) {
    if (t + 2 < NKT)
      stage_slot(sm[(t + 2) & 3], gA + (t + 2) * 32, gB + (t + 2) * 32, tid);

    const u16* sA = sm[t & 3];
    const u16* sB = sm[t & 3] + 8192;
    bf16x8 af[8], bv[4];
#pragma unroll
    for (int mi = 0; mi < 8; ++mi)
      af[mi] = *(const bf16x8*)&sA[(wm + mi * 16 + l15) * 32 + qdsw];
#pragma unroll
    for (int ni = 0; ni < 4; ++ni)
      bv[ni] = *(const bf16x8*)&sB[(wn + ni * 16 + l15) * 32 + qdsw];

    __builtin_amdgcn_s_setprio(1);
#pragma unroll
    for (int mi = 0; mi < 8; ++mi)
#pragma unroll
      for (int ni = 0; ni < 4; ++ni)
        acc[mi][ni] = MFMA(af[mi], bv[ni], acc[mi][ni], 0, 0, 0);
    __builtin_amdgcn_s_setprio(0);

    __builtin_amdgcn_sched_barrier(0);
    if (t + 2 < NKT) {
      asm volatile("s_waitcnt vmcnt(4)" ::: "memory");  // slot t+1 landed
    } else {
      asm volatile("s_waitcnt vmcnt(0)" ::: "memory");  // tail drain
    }
    __builtin_amdgcn_s_barrier();
    __builtin_amdgcn_sched_barrier(0);
  }
}

// ---------------------------------------------------------------------------
// Fused QKV projection: A=x16 [16512][1024] (M-tail tile reads 128 rows past
// the end -> lands in Wqkv16 region, valid memory; stores row-guarded).
// Grid 65*12 flat; nt 0..3 -> q, 4..7 -> k, 8..11 -> v (256 cols each).
// ---------------------------------------------------------------------------
__global__ __launch_bounds__(512, 2) void gemm_qkv(
    const u16* __restrict__ A, const u16* __restrict__ B,
    u16* __restrict__ Cq, u16* __restrict__ Ck, u16* __restrict__ Cv)
{
  __shared__ u16 sm[4][16384];
  const int tid = threadIdx.x;
  f32x4 acc[8][4];
#pragma unroll
  for (int mi = 0; mi < 8; ++mi)
#pragma unroll
    for (int ni = 0; ni < 4; ++ni)
      acc[mi][ni] = (f32x4){0.f, 0.f, 0.f, 0.f};

  const int wg = xcd_swz(blockIdx.x, 65 * 12);
  const int nt = wg % 12, mt = wg / 12;   // nt fastest: A-tile reuse per XCD
  const int m0 = mt * 256, n0 = nt * 256;

  gemm_pipe256(A, B, m0, n0, tid, sm, acc);

  u16* C = nt < 4 ? Cq : (nt < 8 ? Ck : Cv);
  const int c0 = (nt & 3) * 256;
  const int lane = tid & 63, w = tid >> 6;
  const int qd = lane >> 4, l15 = lane & 15;
  const int wm = (w >> 2) * 128, wn = (w & 3) * 64;
#pragma unroll
  for (int mi = 0; mi < 8; ++mi)
#pragma unroll
    for (int ni = 0; ni < 4; ++ni) {
      const int row0 = m0 + wm + mi * 16 + qd * 4;
      const int col  = c0 + wn + ni * 16 + l15;
#pragma unroll
      for (int r = 0; r < 4; ++r)
        if (row0 + r < MROWS)
          C[(size_t)(row0 + r) * DIMSZ + col] = f2bf(acc[mi][ni][r]);
    }
}

// ---------------------------------------------------------------------------
// Output projection: A=ao bf16 (tail reads land in x16 region, valid),
// B=Wo16 bf16, C=f32 d_out, +bias. Grid 65*4.
// ---------------------------------------------------------------------------
__global__ __launch_bounds__(512, 2) void gemm_out(
    const u16* __restrict__ A, const u16* __restrict__ B,
    float* __restrict__ C, const float* __restrict__ bias)
{
  __shared__ u16 sm[4][16384];
  const int tid = threadIdx.x;
  f32x4 acc[8][4];
#pragma unroll
  for (int mi = 0; mi < 8; ++mi)
#pragma unroll
    for (int ni = 0; ni < 4; ++ni)
      acc[mi][ni] = (f32x4){0.f, 0.f, 0.f, 0.f};

  const int wg = xcd_swz(blockIdx.x, 65 * 4);
  const int nt = wg % 4, mt = wg / 4;
  const int m0 = mt * 256, n0 = nt * 256;

  gemm_pipe256(A, B, m0, n0, tid, sm, acc);

  const int lane = tid & 63, w = tid >> 6;
  const int qd = lane >> 4, l15 = lane & 15;
  const int wm = (w >> 2) * 128, wn = (w & 3) * 64;
#pragma unroll
  for (int mi = 0; mi < 8; ++mi)
#pragma unroll
    for (int ni = 0; ni < 4; ++ni) {
      const int row0 = m0 + wm + mi * 16 + qd * 4;
      const int col  = n0 + wn + ni * 16 + l15;
      float badd = bias[col];
#pragma unroll
      for (int r = 0; r < 4; ++r)
        if (row0 + r < MROWS)
          C[(size_t)(row0 + r) * DIMSZ + col] = acc[mi][ni][r] + badd;
    }
}

// ---------------------------------------------------------------------------
// Global attention among the 32 block-leader tokens, per (b,h). One wave/WG.
// ---------------------------------------------------------------------------
__global__ __launch_bounds__(64) void global_attn(
    const u16* __restrict__ q, const u16* __restrict__ k,
    const u16* __restrict__ v, float* __restrict__ g)
{
  __shared__ float sQ[NBLK * 64];
  __shared__ float sKT[64 * NBLK];
  __shared__ float sV[NBLK * 64];
  __shared__ float sp[NBLK];
  const int b = blockIdx.x >> 4, h = blockIdx.x & 15;
  const int lane = threadIdx.x;

  for (int idx = lane; idx < NBLK * 64; idx += 64) {
    int j = idx >> 6, d = idx & 63;
    size_t off = ((size_t)(b * NTOK + j * BLKSZ)) * DIMSZ + h * 64 + d;
    sQ[idx] = bf2f(q[off]);
    sKT[d * NBLK + j] = bf2f(k[off]);
    sV[idx] = bf2f(v[off]);
  }
  __syncthreads();

  for (int i = 0; i < NBLK; ++i) {
    float s = -3.0e38f;
    if (lane < 32) {
      float acc = 0.f;
      for (int d = 0; d < 64; ++d) acc += sQ[i * 64 + d] * sKT[d * NBLK + lane];
      s = acc * 0.125f;
    }
    float m = s;
    for (int t = 1; t < 64; t <<= 1) m = fmaxf(m, __shfl_xor(m, t));
    float e = (lane < 32) ? __expf(s - m) : 0.f;
    float sum = e;
    for (int t = 1; t < 64; t <<= 1) sum += __shfl_xor(sum, t);
    if (lane < 32) sp[lane] = e / sum;
    __syncthreads();
    float acc = 0.f;
    for (int jj = 0; jj < NBLK; ++jj) acc += sp[jj] * sV[jj * 64 + lane];
    g[(((size_t)b * NBLK + i) * HEADS + h) * 64 + lane] = acc;
    __syncthreads();
  }
}

// ---------------------------------------------------------------------------
// MFMA block-local attention, 512 threads (8 waves) per (b, blk, h).
// LDS: sS 144xSSTR (43.8 KB), sKV union (20.7 KB) -> 64.5 KB, 2 WG/CU,
// 16 waves/CU. Strides 152/72 cut 4-16-way LDS bank aliasing to <=2-way.
// Writes ao IN PLACE over q (disjoint WG slices; q reads precede stores).
// ---------------------------------------------------------------------------
__global__ __launch_bounds__(512) void block_attn(
    const u16* q, const u16* __restrict__ k,
    const u16* __restrict__ v, const float* __restrict__ g,
    u16* ao)
{
  __shared__ u16 sS[144 * SSTR];    // scores then P (bf16)
  __shared__ u16 sKV[144 * KSTR];   // phase1: K [key][d] (KSTR); phase3: V^T [dv][key] (SSTR)
  const int b = blockIdx.x, blk = blockIdx.y, h = blockIdx.z;
  const int tid = threadIdx.x, lane = tid & 63, w = tid >> 6;
  const int qd = lane >> 4, l15 = lane & 15;
  const int h64 = h * 64;
  const size_t row_base = (size_t)b * NTOK + (size_t)blk * BLKSZ;
  const f32x4 zero4 = {0.f, 0.f, 0.f, 0.f};

  // ---- K tile [key][d], rows 129..143 zeroed ----
  {
    const u16x8 zero8 = {0, 0, 0, 0, 0, 0, 0, 0};
    for (int c = tid; c < 144 * 8; c += 512) {
      int row = c >> 3, cc = c & 7;
      u16x8 val = zero8;
      if (row < BLKSZ)
        val = *(const u16x8*)(k + (row_base + row) * DIMSZ + h64 + cc * 8);
      *(u16x8*)&sKV[row * KSTR + cc * 8] = val;
    }
  }
  __syncthreads();

  // ---- phase 1: S = 0.125 * Q K^T (81 tiles over 8 waves) ----
  for (int t = w; t < 81; t += 8) {
    int mt = t / 9, nt = t - mt * 9;
    int qrow = mt * 16 + l15;
    if (qrow > 128) qrow = 128;        // clamp: keep reads in-bounds
    const u16* qp = q + (row_base + qrow) * DIMSZ + h64;
    bf16x8 qf0 = *(const bf16x8*)(qp + qd * 8);
    bf16x8 qf1 = *(const bf16x8*)(qp + 32 + qd * 8);
    bf16x8 kf0 = *(const bf16x8*)&sKV[(nt * 16 + l15) * KSTR + qd * 8];
    bf16x8 kf1 = *(const bf16x8*)&sKV[(nt * 16 + l15) * KSTR + 32 + qd * 8];
    f32x4 c = zero4;
    c = MFMA(qf0, kf0, c, 0, 0, 0);
    c = MFMA(qf1, kf1, c, 0, 0, 0);
    int r0 = mt * 16 + qd * 4, col = nt * 16 + l15;
#pragma unroll
    for (int r = 0; r < 4; ++r)
      sS[(r0 + r) * SSTR + col] = f2bf(c[r] * 0.125f);
  }
  __syncthreads();

  // ---- V^T [dv][key] stride SSTR into sKV (K tile dead) ----
  for (int c = tid; c < BLKSZ * 8; c += 512) {
    int row = c >> 3, cc = c & 7;      // row = key index
    u16x8 val = *(const u16x8*)(v + (row_base + row) * DIMSZ + h64 + cc * 8);
#pragma unroll
    for (int jj = 0; jj < 8; ++jj)
      sKV[(cc * 8 + jj) * SSTR + row] = val[jj];
  }

  // ---- softmax over 129 keys (rows over 8 waves) ----
  for (int row = w; row < BLKSZ; row += 8) {
    float x1 = bf2f(sS[row * SSTR + lane]);
    float x2 = bf2f(sS[row * SSTR + 64 + lane]);
    float x3 = (lane == 0) ? bf2f(sS[row * SSTR + 128]) : -3.0e38f;
    float m = fmaxf(fmaxf(x1, x2), x3);
    for (int t = 1; t < 64; t <<= 1) m = fmaxf(m, __shfl_xor(m, t));
    float e1 = __expf(x1 - m), e2 = __expf(x2 - m);
    float e3 = (lane == 0) ? __expf(x3 - m) : 0.f;
    float s = e1 + e2 + e3;
    for (int t = 1; t < 64; t <<= 1) s += __shfl_xor(s, t);
    float inv = 1.f / s;
    sS[row * SSTR + lane] = f2bf(e1 * inv);
    sS[row * SSTR + 64 + lane] = f2bf(e2 * inv);
    if (lane == 0) sS[row * SSTR + 128] = f2bf(e3 * inv);
  }
  __syncthreads();

  // ---- phase 3: out = P V (keys 0..127 MFMA + rank-1 key 128) ----
  for (int t = w; t < 36; t += 8) {
    int mt = t >> 2, nt = t & 3;
    f32x4 c = zero4;
#pragma unroll
    for (int kk = 0; kk < 128; kk += 32) {
      bf16x8 pf = *(const bf16x8*)&sS[(mt * 16 + l15) * SSTR + kk + qd * 8];
      bf16x8 vf = *(const bf16x8*)&sKV[(nt * 16 + l15) * SSTR + kk + qd * 8];
      c = MFMA(pf, vf, c, 0, 0, 0);
    }
    int dv = nt * 16 + l15;
    float v128 = bf2f(sKV[dv * SSTR + 128]);
    int r0 = mt * 16 + qd * 4;
#pragma unroll
    for (int r = 0; r < 4; ++r) {
      int row = r0 + r;
      if (row < BLKSZ) {
        float p128 = bf2f(sS[row * SSTR + 128]);
        float val = c[r] + p128 * v128;
        if (row == 0)
          val += g[(((size_t)b * NBLK + blk) * HEADS + h) * 64 + dv];
        ao[(row_base + row) * DIMSZ + h64 + dv] = f2bf(val);
      }
    }
  }
}

// ---------------------------------------------------------------------------
extern "C" void kernel_launch(void* const* d_in, const int* in_sizes, int n_in,
                              void* d_out, int out_size, void* d_ws, size_t ws_size,
                              hipStream_t stream) {
  // Inputs f32; OUTPUT f32 (round-8 verified).
  const float* x  = (const float*)d_in[0];
  const float* Wq = (const float*)d_in[1];
  const float* Wk = (const float*)d_in[2];
  const float* Wv = (const float*)d_in[3];
  const float* Wo = (const float*)d_in[4];
  const float* bo = (const float*)d_in[5];
  float* out = (float*)d_out;

  // Scratch:
  //   d_out (67.6 MB) during attention: [k bf16 33.8][v bf16 33.8]
  //   d_ws (74.6 MB peak):
  //     [0,1MB) g | [1,+33.8) qb (ao in-place) | [+33.8) x16 | [+6MB) Wqkv16
  //   Wo16 reuses the x16 region (cast launched after gemm_qkv, stream-ordered).
  char* ws = (char*)d_ws;
  const size_t xb = (size_t)MROWS * DIMSZ * sizeof(u16);   // 33.8 MB
  float* gb     = (float*)ws;
  u16*   qb     = (u16*)(ws + (1u << 20));
  u16*   x16    = (u16*)(ws + (1u << 20) + xb);
  u16*   Wqkv16 = (u16*)(ws + (1u << 20) + 2 * xb);
  u16*   Wo16   = x16;                     // reused after gemm_qkv
  u16*   kb     = (u16*)d_out;
  u16*   vb     = (u16*)d_out + (size_t)MROWS * DIMSZ;

  const int nx = MROWS * DIMSZ;
  const int nw = DIMSZ * DIMSZ;
  cast_f32_bf16<<<nx / 1024, 256, 0, stream>>>(x,  x16, nx);
  cast_f32_bf16<<<nw / 1024, 256, 0, stream>>>(Wq, Wqkv16,          nw);
  cast_f32_bf16<<<nw / 1024, 256, 0, stream>>>(Wk, Wqkv16 + nw,     nw);
  cast_f32_bf16<<<nw / 1024, 256, 0, stream>>>(Wv, Wqkv16 + 2 * nw, nw);

  gemm_qkv<<<dim3(65 * 12), 512, 0, stream>>>(x16, Wqkv16, qb, kb, vb);

  cast_f32_bf16<<<nw / 1024, 256, 0, stream>>>(Wo, Wo16, nw);   // after qkv: x16 dead

  global_attn<<<dim3(BATCH * HEADS), 64, 0, stream>>>(qb, kb, vb, gb);
  block_attn<<<dim3(BATCH, NBLK, HEADS), 512, 0, stream>>>(qb, kb, vb, gb, qb);
  gemm_out<<<dim3(65 * 4), 512, 0, stream>>>(qb, Wo16, out, bo);
}

// Round 3
// 466.730 us; speedup vs baseline: 1.0387x; 1.0387x over previous
//
#include <hip/hip_runtime.h>

typedef unsigned short u16;
typedef __attribute__((ext_vector_type(8))) __bf16 bf16x8;
typedef __attribute__((ext_vector_type(4))) float f32x4;
typedef __attribute__((ext_vector_type(8))) u16 u16x8;
typedef __attribute__((ext_vector_type(4))) u16 u16x4;

#define DIMSZ 1024
#define HEADS 16
#define BLKSZ 129
#define NBLK 32
#define NTOK (BLKSZ * NBLK)      // 4128
#define BATCH 4
#define MROWS (BATCH * NTOK)     // 16512

#define MFMA __builtin_amdgcn_mfma_f32_16x16x32_bf16

#define SSTR 152   // S/P LDS row stride (bf16): 2-way bank alias only (free)
#define KSTR 72    // K tile LDS row stride

#define NKT 32     // K tiles of 32: 1024/32

__device__ __forceinline__ float bf2f(u16 u) {
  return __uint_as_float(((unsigned)u) << 16);
}
__device__ __forceinline__ u16 f2bf(float f) {
  unsigned u = __float_as_uint(f);
  u += 0x7FFFu + ((u >> 16) & 1u);   // round-to-nearest-even
  return (u16)(u >> 16);
}

// async global->LDS, 16B/lane; LDS dest = wave-uniform base + lane*16 (m97)
#define GLD16(ldsp, gp) __builtin_amdgcn_global_load_lds( \
    (const __attribute__((address_space(1))) void*)(gp),   \
    (__attribute__((address_space(3))) void*)(ldsp), 16, 0, 0)

// ---------------------------------------------------------------------------
// f32 -> bf16 cast, 4 elems/thread. n multiple of 1024.
// ---------------------------------------------------------------------------
__global__ __launch_bounds__(256) void cast_f32_bf16(
    const float* __restrict__ in, u16* __restrict__ out, int n)
{
  int i = (blockIdx.x * 256 + threadIdx.x) * 4;
  if (i < n) {
    float4 f = *(const float4*)(in + i);
    u16x4 o = { f2bf(f.x), f2bf(f.y), f2bf(f.z), f2bf(f.w) };
    *(u16x4*)(out + i) = o;
  }
}

// ---------------------------------------------------------------------------
// Bijective XCD-aware block swizzle (m204): contiguous logical chunk per XCD.
// ---------------------------------------------------------------------------
__device__ __forceinline__ int xcd_swz(int bid, int nwg) {
  const int xcd = bid & 7, l = bid >> 3;
  const int q = nwg >> 3, r = nwg & 7;
  return (xcd < r ? xcd * (q + 1) : r * (q + 1) + (xcd - r) * q) + l;
}

// ---------------------------------------------------------------------------
// Stage one BK=32 slot (A 256x32 + B 256x32 = 32KB) for the 256-wide pipe.
// Source cols pre-swizzled (chunk ^= (row>>1)&3); LDS dest linear (rule #21).
// ---------------------------------------------------------------------------
__device__ __forceinline__ void stage_slot(u16* slot, const u16* gA,
                                           const u16* gB, int tid) {
  GLD16(slot + tid * 8, gA);                       // A rows 0..127
  GLD16(slot + 4096 + tid * 8, gA + 128 * DIMSZ);  // A rows 128..255
  GLD16(slot + 8192 + tid * 8, gB);                // B rows 0..127
  GLD16(slot + 12288 + tid * 8, gB + 128 * DIMSZ); // B rows 128..255
}

// ---------------------------------------------------------------------------
// 256x256 pipelined GEMM mainloop, BK=32, 8 waves (2M x 4N), wave tile
// 128x64 (acc[8][4]). 4-slot LDS ring (128 KB), counted vmcnt(4).
// T3 phase-split: each K-step is 2 phases at m201 density (16 MFMA +
// 4-8 ds_read + 2 global_load_lds per phase, barrier between read-issue and
// MFMA cluster). Waves arrive staggered -> one wave's MFMA overlaps another
// wave's ds_reads; setprio(1) (T5) prefers the MFMA-entering waves.
// Ring hazards: slot t+2 was last read at step t-2 (>=2 barriers ago);
// vmcnt(4) at step end retires exactly slot t+1's 4 loads.
// ---------------------------------------------------------------------------
__device__ __forceinline__ void gemm_pipe256(
    const u16* __restrict__ A, const u16* __restrict__ Bm,
    int m0, int n0, int tid, u16 (*sm)[16384], f32x4 (*acc)[4])
{
  const int lane = tid & 63, w = tid >> 6;
  const int qd = lane >> 4, l15 = lane & 15;
  const int wm = (w >> 2) * 128, wn = (w & 3) * 64;
  // read-side swizzle: chunk qd ^ ((row>>1)&3); lane-constant (rows 16-aligned)
  const int qdsw = (qd ^ ((l15 >> 1) & 3)) * 8;

  const int srow = tid >> 2;
  const int schk = (tid & 3) ^ ((tid >> 3) & 3);
  const u16* gA = A + (size_t)(m0 + srow) * DIMSZ + schk * 8;
  const u16* gB = Bm + (size_t)(n0 + srow) * DIMSZ + schk * 8;

  // prologue: stage slots 0,1; land slot 0, keep slot 1's 4 loads in flight
  stage_slot(sm[0], gA, gB, tid);
  stage_slot(sm[1], gA + 32, gB + 32, tid);
  asm volatile("s_waitcnt vmcnt(4)" ::: "memory");
  __builtin_amdgcn_s_barrier();
  __builtin_amdgcn_sched_barrier(0);

#pragma unroll 4
  for (int t = 0; t < NKT; ++t) {
    const u16* sA = sm[t & 3];
    const u16* sB = sm[t & 3] + 8192;
    u16* sl2 = sm[(t + 2) & 3];
    const u16* gA2 = gA + (t + 2) * 32;
    const u16* gB2 = gB + (t + 2) * 32;
    const bool pf = (t + 2 < NKT);

    // ---- phase 1: read af[0..3]+bv[0..3]; stage A-halves of t+2 ----
    bf16x8 af[4], bv[4];
#pragma unroll
    for (int mi = 0; mi < 4; ++mi)
      af[mi] = *(const bf16x8*)&sA[(wm + mi * 16 + l15) * 32 + qdsw];
#pragma unroll
    for (int ni = 0; ni < 4; ++ni)
      bv[ni] = *(const bf16x8*)&sB[(wn + ni * 16 + l15) * 32 + qdsw];
    if (pf) {
      GLD16(sl2 + tid * 8, gA2);
      GLD16(sl2 + 4096 + tid * 8, gA2 + 128 * DIMSZ);
    }
    __builtin_amdgcn_sched_barrier(0);
    __builtin_amdgcn_s_barrier();
    __builtin_amdgcn_s_setprio(1);
#pragma unroll
    for (int mi = 0; mi < 4; ++mi)
#pragma unroll
      for (int ni = 0; ni < 4; ++ni)
        acc[mi][ni] = MFMA(af[mi], bv[ni], acc[mi][ni], 0, 0, 0);
    __builtin_amdgcn_s_setprio(0);
    __builtin_amdgcn_sched_barrier(0);

    // ---- phase 2: read af[4..7]; stage B-halves of t+2 ----
    bf16x8 ag[4];
#pragma unroll
    for (int mi = 0; mi < 4; ++mi)
      ag[mi] = *(const bf16x8*)&sA[(wm + 64 + mi * 16 + l15) * 32 + qdsw];
    if (pf) {
      GLD16(sl2 + 8192 + tid * 8, gB2);
      GLD16(sl2 + 12288 + tid * 8, gB2 + 128 * DIMSZ);
    }
    __builtin_amdgcn_sched_barrier(0);
    __builtin_amdgcn_s_barrier();
    __builtin_amdgcn_s_setprio(1);
#pragma unroll
    for (int mi = 0; mi < 4; ++mi)
#pragma unroll
      for (int ni = 0; ni < 4; ++ni)
        acc[mi + 4][ni] = MFMA(ag[mi], bv[ni], acc[mi + 4][ni], 0, 0, 0);
    __builtin_amdgcn_s_setprio(0);
    __builtin_amdgcn_sched_barrier(0);

    if (pf) {
      asm volatile("s_waitcnt vmcnt(4)" ::: "memory");  // slot t+1 landed
    } else {
      asm volatile("s_waitcnt vmcnt(0)" ::: "memory");  // tail drain
    }
    __builtin_amdgcn_s_barrier();
    __builtin_amdgcn_sched_barrier(0);
  }
}

// ---------------------------------------------------------------------------
// 128x256 pipelined GEMM mainloop, BK=32, 8 waves (2M x 4N), wave tile
// 64x64 (acc[4][4]). 3-slot ring (72 KB -> 2 WG/CU: inter-WG TLP covers
// the overlap), counted vmcnt(3). Slot staged at step t is (t+2)%3 =
// (t-1)%3, whose reads were drained before step t-1's end barrier.
// ---------------------------------------------------------------------------
__device__ __forceinline__ void stage_slot128(u16* slot, const u16* gA,
                                              const u16* gB, int tid) {
  GLD16(slot + tid * 8, gA);                       // A rows 0..127
  GLD16(slot + 4096 + tid * 8, gB);                // B rows 0..127
  GLD16(slot + 8192 + tid * 8, gB + 128 * DIMSZ);  // B rows 128..255
}

__device__ __forceinline__ void gemm_pipe128(
    const u16* __restrict__ A, const u16* __restrict__ Bm,
    int m0, int n0, int tid, u16 (*sm)[12288], f32x4 (*acc)[4])
{
  const int lane = tid & 63, w = tid >> 6;
  const int qd = lane >> 4, l15 = lane & 15;
  const int wm = (w >> 2) * 64, wn = (w & 3) * 64;
  const int qdsw = (qd ^ ((l15 >> 1) & 3)) * 8;

  const int srow = tid >> 2;
  const int schk = (tid & 3) ^ ((tid >> 3) & 3);
  const u16* gA = A + (size_t)(m0 + srow) * DIMSZ + schk * 8;
  const u16* gB = Bm + (size_t)(n0 + srow) * DIMSZ + schk * 8;

  u16 *p0 = sm[0], *p1 = sm[1], *p2 = sm[2];
  stage_slot128(p0, gA, gB, tid);
  stage_slot128(p1, gA + 32, gB + 32, tid);
  asm volatile("s_waitcnt vmcnt(3)" ::: "memory");
  __builtin_amdgcn_s_barrier();
  __builtin_amdgcn_sched_barrier(0);

  for (int t = 0; t < NKT; ++t) {
    const bool pf = (t + 2 < NKT);
    if (pf)
      stage_slot128(p2, gA + (t + 2) * 32, gB + (t + 2) * 32, tid);

    bf16x8 af[4], bv[4];
#pragma unroll
    for (int mi = 0; mi < 4; ++mi)
      af[mi] = *(const bf16x8*)&p0[(wm + mi * 16 + l15) * 32 + qdsw];
#pragma unroll
    for (int ni = 0; ni < 4; ++ni)
      bv[ni] = *(const bf16x8*)&p0[4096 + (wn + ni * 16 + l15) * 32 + qdsw];

    __builtin_amdgcn_sched_barrier(0);
    __builtin_amdgcn_s_setprio(1);
#pragma unroll
    for (int mi = 0; mi < 4; ++mi)
#pragma unroll
      for (int ni = 0; ni < 4; ++ni)
        acc[mi][ni] = MFMA(af[mi], bv[ni], acc[mi][ni], 0, 0, 0);
    __builtin_amdgcn_s_setprio(0);
    __builtin_amdgcn_sched_barrier(0);

    if (pf) {
      asm volatile("s_waitcnt vmcnt(3)" ::: "memory");  // slot t+1 landed
    } else {
      asm volatile("s_waitcnt vmcnt(0)" ::: "memory");
    }
    __builtin_amdgcn_s_barrier();
    __builtin_amdgcn_sched_barrier(0);

    u16* tmp = p0; p0 = p1; p1 = p2; p2 = tmp;   // rotate ring
  }
}

// ---------------------------------------------------------------------------
// Fused QKV projection: A=x16 [16512][1024] (M-tail tile reads 128 rows past
// the end -> lands in Wqkv16 region, valid memory; stores row-guarded).
// Grid 65*12 flat; nt 0..3 -> q, 4..7 -> k, 8..11 -> v (256 cols each).
// ---------------------------------------------------------------------------
__global__ __launch_bounds__(512, 2) void gemm_qkv(
    const u16* __restrict__ A, const u16* __restrict__ B,
    u16* __restrict__ Cq, u16* __restrict__ Ck, u16* __restrict__ Cv)
{
  __shared__ u16 sm[4][16384];
  const int tid = threadIdx.x;
  f32x4 acc[8][4];
#pragma unroll
  for (int mi = 0; mi < 8; ++mi)
#pragma unroll
    for (int ni = 0; ni < 4; ++ni)
      acc[mi][ni] = (f32x4){0.f, 0.f, 0.f, 0.f};

  const int wg = xcd_swz(blockIdx.x, 65 * 12);
  const int nt = wg % 12, mt = wg / 12;   // nt fastest: A-tile reuse per XCD
  const int m0 = mt * 256, n0 = nt * 256;

  gemm_pipe256(A, B, m0, n0, tid, sm, acc);

  u16* C = nt < 4 ? Cq : (nt < 8 ? Ck : Cv);
  const int c0 = (nt & 3) * 256;
  const int lane = tid & 63, w = tid >> 6;
  const int qd = lane >> 4, l15 = lane & 15;
  const int wm = (w >> 2) * 128, wn = (w & 3) * 64;
#pragma unroll
  for (int mi = 0; mi < 8; ++mi)
#pragma unroll
    for (int ni = 0; ni < 4; ++ni) {
      const int row0 = m0 + wm + mi * 16 + qd * 4;
      const int col  = c0 + wn + ni * 16 + l15;
#pragma unroll
      for (int r = 0; r < 4; ++r)
        if (row0 + r < MROWS)
          C[(size_t)(row0 + r) * DIMSZ + col] = f2bf(acc[mi][ni][r]);
    }
}

// ---------------------------------------------------------------------------
// Output projection: A=ao bf16, B=Wo16 bf16, C=f32 d_out, +bias.
// Grid 129*4 (exact M fit, no guards), 2 WG/CU.
// ---------------------------------------------------------------------------
__global__ __launch_bounds__(512, 4) void gemm_out(
    const u16* __restrict__ A, const u16* __restrict__ B,
    float* __restrict__ C, const float* __restrict__ bias)
{
  __shared__ u16 sm[3][12288];
  const int tid = threadIdx.x;
  f32x4 acc[4][4];
#pragma unroll
  for (int mi = 0; mi < 4; ++mi)
#pragma unroll
    for (int ni = 0; ni < 4; ++ni)
      acc[mi][ni] = (f32x4){0.f, 0.f, 0.f, 0.f};

  const int wg = xcd_swz(blockIdx.x, 129 * 4);
  const int nt = wg & 3, mt = wg >> 2;
  const int m0 = mt * 128, n0 = nt * 256;

  gemm_pipe128(A, B, m0, n0, tid, sm, acc);

  const int lane = tid & 63, w = tid >> 6;
  const int qd = lane >> 4, l15 = lane & 15;
  const int wm = (w >> 2) * 64, wn = (w & 3) * 64;
#pragma unroll
  for (int mi = 0; mi < 4; ++mi)
#pragma unroll
    for (int ni = 0; ni < 4; ++ni) {
      const int row0 = m0 + wm + mi * 16 + qd * 4;
      const int col  = n0 + wn + ni * 16 + l15;
      float badd = bias[col];
#pragma unroll
      for (int r = 0; r < 4; ++r)
        C[(size_t)(row0 + r) * DIMSZ + col] = acc[mi][ni][r] + badd;
    }
}

// ---------------------------------------------------------------------------
// Global attention among the 32 block-leader tokens, per (b,h). One wave/WG.
// ---------------------------------------------------------------------------
__global__ __launch_bounds__(64) void global_attn(
    const u16* __restrict__ q, const u16* __restrict__ k,
    const u16* __restrict__ v, float* __restrict__ g)
{
  __shared__ float sQ[NBLK * 64];
  __shared__ float sKT[64 * NBLK];
  __shared__ float sV[NBLK * 64];
  __shared__ float sp[NBLK];
  const int b = blockIdx.x >> 4, h = blockIdx.x & 15;
  const int lane = threadIdx.x;

  for (int idx = lane; idx < NBLK * 64; idx += 64) {
    int j = idx >> 6, d = idx & 63;
    size_t off = ((size_t)(b * NTOK + j * BLKSZ)) * DIMSZ + h * 64 + d;
    sQ[idx] = bf2f(q[off]);
    sKT[d * NBLK + j] = bf2f(k[off]);
    sV[idx] = bf2f(v[off]);
  }
  __syncthreads();

  for (int i = 0; i < NBLK; ++i) {
    float s = -3.0e38f;
    if (lane < 32) {
      float acc = 0.f;
      for (int d = 0; d < 64; ++d) acc += sQ[i * 64 + d] * sKT[d * NBLK + lane];
      s = acc * 0.125f;
    }
    float m = s;
    for (int t = 1; t < 64; t <<= 1) m = fmaxf(m, __shfl_xor(m, t));
    float e = (lane < 32) ? __expf(s - m) : 0.f;
    float sum = e;
    for (int t = 1; t < 64; t <<= 1) sum += __shfl_xor(sum, t);
    if (lane < 32) sp[lane] = e / sum;
    __syncthreads();
    float acc = 0.f;
    for (int jj = 0; jj < NBLK; ++jj) acc += sp[jj] * sV[jj * 64 + lane];
    g[(((size_t)b * NBLK + i) * HEADS + h) * 64 + lane] = acc;
    __syncthreads();
  }
}

// ---------------------------------------------------------------------------
// MFMA block-local attention, 512 threads (8 waves) per (b, blk, h).
// LDS: sS 144xSSTR (43.8 KB), sKV union (20.7 KB) -> 64.5 KB, 2 WG/CU,
// 16 waves/CU. Strides 152/72 cut 4-16-way LDS bank aliasing to <=2-way.
// Writes ao IN PLACE over q (disjoint WG slices; q reads precede stores).
// ---------------------------------------------------------------------------
__global__ __launch_bounds__(512) void block_attn(
    const u16* q, const u16* __restrict__ k,
    const u16* __restrict__ v, const float* __restrict__ g,
    u16* ao)
{
  __shared__ u16 sS[144 * SSTR];    // scores then P (bf16)
  __shared__ u16 sKV[144 * KSTR];   // phase1: K [key][d] (KSTR); phase3: V^T [dv][key] (SSTR)
  const int b = blockIdx.x, blk = blockIdx.y, h = blockIdx.z;
  const int tid = threadIdx.x, lane = tid & 63, w = tid >> 6;
  const int qd = lane >> 4, l15 = lane & 15;
  const int h64 = h * 64;
  const size_t row_base = (size_t)b * NTOK + (size_t)blk * BLKSZ;
  const f32x4 zero4 = {0.f, 0.f, 0.f, 0.f};

  // ---- K tile [key][d], rows 129..143 zeroed ----
  {
    const u16x8 zero8 = {0, 0, 0, 0, 0, 0, 0, 0};
    for (int c = tid; c < 144 * 8; c += 512) {
      int row = c >> 3, cc = c & 7;
      u16x8 val = zero8;
      if (row < BLKSZ)
        val = *(const u16x8*)(k + (row_base + row) * DIMSZ + h64 + cc * 8);
      *(u16x8*)&sKV[row * KSTR + cc * 8] = val;
    }
  }
  __syncthreads();

  // ---- phase 1: S = 0.125 * Q K^T (81 tiles over 8 waves) ----
  for (int t = w; t < 81; t += 8) {
    int mt = t / 9, nt = t - mt * 9;
    int qrow = mt * 16 + l15;
    if (qrow > 128) qrow = 128;        // clamp: keep reads in-bounds
    const u16* qp = q + (row_base + qrow) * DIMSZ + h64;
    bf16x8 qf0 = *(const bf16x8*)(qp + qd * 8);
    bf16x8 qf1 = *(const bf16x8*)(qp + 32 + qd * 8);
    bf16x8 kf0 = *(const bf16x8*)&sKV[(nt * 16 + l15) * KSTR + qd * 8];
    bf16x8 kf1 = *(const bf16x8*)&sKV[(nt * 16 + l15) * KSTR + 32 + qd * 8];
    f32x4 c = zero4;
    c = MFMA(qf0, kf0, c, 0, 0, 0);
    c = MFMA(qf1, kf1, c, 0, 0, 0);
    int r0 = mt * 16 + qd * 4, col = nt * 16 + l15;
#pragma unroll
    for (int r = 0; r < 4; ++r)
      sS[(r0 + r) * SSTR + col] = f2bf(c[r] * 0.125f);
  }
  __syncthreads();

  // ---- V^T [dv][key] stride SSTR into sKV (K tile dead) ----
  for (int c = tid; c < BLKSZ * 8; c += 512) {
    int row = c >> 3, cc = c & 7;      // row = key index
    u16x8 val = *(const u16x8*)(v + (row_base + row) * DIMSZ + h64 + cc * 8);
#pragma unroll
    for (int jj = 0; jj < 8; ++jj)
      sKV[(cc * 8 + jj) * SSTR + row] = val[jj];
  }

  // ---- softmax over 129 keys (rows over 8 waves) ----
  for (int row = w; row < BLKSZ; row += 8) {
    float x1 = bf2f(sS[row * SSTR + lane]);
    float x2 = bf2f(sS[row * SSTR + 64 + lane]);
    float x3 = (lane == 0) ? bf2f(sS[row * SSTR + 128]) : -3.0e38f;
    float m = fmaxf(fmaxf(x1, x2), x3);
    for (int t = 1; t < 64; t <<= 1) m = fmaxf(m, __shfl_xor(m, t));
    float e1 = __expf(x1 - m), e2 = __expf(x2 - m);
    float e3 = (lane == 0) ? __expf(x3 - m) : 0.f;
    float s = e1 + e2 + e3;
    for (int t = 1; t < 64; t <<= 1) s += __shfl_xor(s, t);
    float inv = 1.f / s;
    sS[row * SSTR + lane] = f2bf(e1 * inv);
    sS[row * SSTR + 64 + lane] = f2bf(e2 * inv);
    if (lane == 0) sS[row * SSTR + 128] = f2bf(e3 * inv);
  }
  __syncthreads();

  // ---- phase 3: out = P V (keys 0..127 MFMA + rank-1 key 128) ----
  for (int t = w; t < 36; t += 8) {
    int mt = t >> 2, nt = t & 3;
    f32x4 c = zero4;
#pragma unroll
    for (int kk = 0; kk < 128; kk += 32) {
      bf16x8 pf = *(const bf16x8*)&sS[(mt * 16 + l15) * SSTR + kk + qd * 8];
      bf16x8 vf = *(const bf16x8*)&sKV[(nt * 16 + l15) * SSTR + kk + qd * 8];
      c = MFMA(pf, vf, c, 0, 0, 0);
    }
    int dv = nt * 16 + l15;
    float v128 = bf2f(sKV[dv * SSTR + 128]);
    int r0 = mt * 16 + qd * 4;
#pragma unroll
    for (int r = 0; r < 4; ++r) {
      int row = r0 + r;
      if (row < BLKSZ) {
        float p128 = bf2f(sS[row * SSTR + 128]);
        float val = c[r] + p128 * v128;
        if (row == 0)
          val += g[(((size_t)b * NBLK + blk) * HEADS + h) * 64 + dv];
        ao[(row_base + row) * DIMSZ + h64 + dv] = f2bf(val);
      }
    }
  }
}

// ---------------------------------------------------------------------------
extern "C" void kernel_launch(void* const* d_in, const int* in_sizes, int n_in,
                              void* d_out, int out_size, void* d_ws, size_t ws_size,
                              hipStream_t stream) {
  // Inputs f32; OUTPUT f32 (round-8 verified).
  const float* x  = (const float*)d_in[0];
  const float* Wq = (const float*)d_in[1];
  const float* Wk = (const float*)d_in[2];
  const float* Wv = (const float*)d_in[3];
  const float* Wo = (const float*)d_in[4];
  const float* bo = (const float*)d_in[5];
  float* out = (float*)d_out;

  // Scratch:
  //   d_out (67.6 MB) during attention: [k bf16 33.8][v bf16 33.8]
  //   d_ws (74.6 MB peak):
  //     [0,1MB) g | [1,+33.8) qb (ao in-place) | [+33.8) x16 | [+6MB) Wqkv16
  //   Wo16 reuses the x16 region (cast launched after gemm_qkv, stream-ordered).
  char* ws = (char*)d_ws;
  const size_t xb = (size_t)MROWS * DIMSZ * sizeof(u16);   // 33.8 MB
  float* gb     = (float*)ws;
  u16*   qb     = (u16*)(ws + (1u << 20));
  u16*   x16    = (u16*)(ws + (1u << 20) + xb);
  u16*   Wqkv16 = (u16*)(ws + (1u << 20) + 2 * xb);
  u16*   Wo16   = x16;                     // reused after gemm_qkv
  u16*   kb     = (u16*)d_out;
  u16*   vb     = (u16*)d_out + (size_t)MROWS * DIMSZ;

  const int nx = MROWS * DIMSZ;
  const int nw = DIMSZ * DIMSZ;
  cast_f32_bf16<<<nx / 1024, 256, 0, stream>>>(x,  x16, nx);
  cast_f32_bf16<<<nw / 1024, 256, 0, stream>>>(Wq, Wqkv16,          nw);
  cast_f32_bf16<<<nw / 1024, 256, 0, stream>>>(Wk, Wqkv16 + nw,     nw);
  cast_f32_bf16<<<nw / 1024, 256, 0, stream>>>(Wv, Wqkv16 + 2 * nw, nw);

  gemm_qkv<<<dim3(65 * 12), 512, 0, stream>>>(x16, Wqkv16, qb, kb, vb);

  cast_f32_bf16<<<nw / 1024, 256, 0, stream>>>(Wo, Wo16, nw);   // after qkv: x16 dead

  global_attn<<<dim3(BATCH * HEADS), 64, 0, stream>>>(qb, kb, vb, gb);
  block_attn<<<dim3(BATCH, NBLK, HEADS), 512, 0, stream>>>(qb, kb, vb, gb, qb);
  gemm_out<<<dim3(129 * 4), 512, 0, stream>>>(qb, Wo16, out, bo);
}

// Round 4
// 432.509 us; speedup vs baseline: 1.1208x; 1.0791x over previous
//
#include <hip/hip_runtime.h>

typedef unsigned short u16;
typedef __attribute__((ext_vector_type(8))) __bf16 bf16x8;
typedef __attribute__((ext_vector_type(4))) float f32x4;
typedef __attribute__((ext_vector_type(8))) u16 u16x8;
typedef __attribute__((ext_vector_type(4))) u16 u16x4;

#define DIMSZ 1024
#define HEADS 16
#define BLKSZ 129
#define NBLK 32
#define NTOK (BLKSZ * NBLK)      // 4128
#define BATCH 4
#define MROWS (BATCH * NTOK)     // 16512

#define MFMA __builtin_amdgcn_mfma_f32_16x16x32_bf16

#define SSTR 152   // S/P LDS row stride (bf16): 2-way bank alias only (free)
#define KSTR 72    // K tile LDS row stride

#define NKT 32     // K tiles of 32: 1024/32

__device__ __forceinline__ float bf2f(u16 u) {
  return __uint_as_float(((unsigned)u) << 16);
}
__device__ __forceinline__ u16 f2bf(float f) {
  unsigned u = __float_as_uint(f);
  u += 0x7FFFu + ((u >> 16) & 1u);   // round-to-nearest-even
  return (u16)(u >> 16);
}

// async global->LDS, 16B/lane; LDS dest = wave-uniform base + lane*16 (m97)
#define GLD16(ldsp, gp) __builtin_amdgcn_global_load_lds( \
    (const __attribute__((address_space(1))) void*)(gp),   \
    (__attribute__((address_space(3))) void*)(ldsp), 16, 0, 0)

// ---------------------------------------------------------------------------
// f32 -> bf16 cast, 4 elems/thread. n multiple of 1024.
// ---------------------------------------------------------------------------
__global__ __launch_bounds__(256) void cast_f32_bf16(
    const float* __restrict__ in, u16* __restrict__ out, int n)
{
  int i = (blockIdx.x * 256 + threadIdx.x) * 4;
  if (i < n) {
    float4 f = *(const float4*)(in + i);
    u16x4 o = { f2bf(f.x), f2bf(f.y), f2bf(f.z), f2bf(f.w) };
    *(u16x4*)(out + i) = o;
  }
}

// ---------------------------------------------------------------------------
// Bijective XCD-aware block swizzle (m204): contiguous logical chunk per XCD.
// ---------------------------------------------------------------------------
__device__ __forceinline__ int xcd_swz(int bid, int nwg) {
  const int xcd = bid & 7, l = bid >> 3;
  const int q = nwg >> 3, r = nwg & 7;
  return (xcd < r ? xcd * (q + 1) : r * (q + 1) + (xcd - r) * q) + l;
}

// ---------------------------------------------------------------------------
// Stage one BK=32 slot (A 128x32 + B 128x32 = 16 KB) with 256 threads:
// 4 x global_load_lds dwordx4 per thread. LDS dest linear (lane*16 rule);
// source cols pre-swizzled (chunk ^= (row>>1)&3) so the swizzled ds_read is
// bank-uniform (rule #21: swizzle source+read, keep DMA dest linear).
// Zero LDS bank conflicts verified on HW (round 2, same pattern).
// ---------------------------------------------------------------------------
__device__ __forceinline__ void stage_sq(u16* slot, const u16* gA,
                                         const u16* gB, int tid) {
  GLD16(slot + tid * 8, gA);                      // A rows 0..63
  GLD16(slot + 2048 + tid * 8, gA + 64 * DIMSZ);  // A rows 64..127
  GLD16(slot + 4096 + tid * 8, gB);               // B rows 0..63
  GLD16(slot + 6144 + tid * 8, gB + 64 * DIMSZ);  // B rows 64..127
}

// ---------------------------------------------------------------------------
// 128x128 pipelined GEMM mainloop: BK=32, 256 threads = 4 waves (2M x 2N),
// wave tile 64x64 (acc[4][4]). 4-slot LDS ring = 64 KB -> 2 WG/CU: one WG's
// LDS-read burst overlaps the other WG's MFMA burst (TLP overlap, no extra
// sync structure). Counted vmcnt(4) + raw s_barrier (1 barrier/step): slot
// t+2's 4 loads stay in flight across the barrier; slot t+2 was last read
// at step t-2 (two barriers ago) -> race-free.
// ---------------------------------------------------------------------------
__device__ __forceinline__ void gemm_pipe_sq(
    const u16* __restrict__ A, const u16* __restrict__ Bm,
    int m0, int n0, int tid, u16 (*sm)[8192], f32x4 (*acc)[4])
{
  const int lane = tid & 63, w = tid >> 6;
  const int qd = lane >> 4, l15 = lane & 15;
  const int wm = (w >> 1) * 64, wn = (w & 1) * 64;
  // read-side swizzle: chunk qd ^ ((row>>1)&3); lane-constant (rows 16-aligned)
  const int qdsw = (qd ^ ((l15 >> 1) & 3)) * 8;

  const int srow = tid >> 2;                      // 0..63
  const int schk = (tid & 3) ^ ((tid >> 3) & 3);  // source chunk swizzle
  const u16* gA = A + (size_t)(m0 + srow) * DIMSZ + schk * 8;
  const u16* gB = Bm + (size_t)(n0 + srow) * DIMSZ + schk * 8;

  // prologue: stage slots 0,1; land slot 0, keep slot 1's 4 loads in flight
  stage_sq(sm[0], gA, gB, tid);
  stage_sq(sm[1], gA + 32, gB + 32, tid);
  asm volatile("s_waitcnt vmcnt(4)" ::: "memory");
  __builtin_amdgcn_s_barrier();
  __builtin_amdgcn_sched_barrier(0);

#pragma unroll 4
  for (int t = 0; t < NKT; ++t) {
    if (t + 2 < NKT)
      stage_sq(sm[(t + 2) & 3], gA + (t + 2) * 32, gB + (t + 2) * 32, tid);

    const u16* slot = sm[t & 3];
    bf16x8 af[4], bv[4];
#pragma unroll
    for (int mi = 0; mi < 4; ++mi)
      af[mi] = *(const bf16x8*)&slot[(wm + mi * 16 + l15) * 32 + qdsw];
#pragma unroll
    for (int ni = 0; ni < 4; ++ni)
      bv[ni] = *(const bf16x8*)&slot[4096 + (wn + ni * 16 + l15) * 32 + qdsw];

    __builtin_amdgcn_s_setprio(1);
#pragma unroll
    for (int mi = 0; mi < 4; ++mi)
#pragma unroll
      for (int ni = 0; ni < 4; ++ni)
        acc[mi][ni] = MFMA(af[mi], bv[ni], acc[mi][ni], 0, 0, 0);
    __builtin_amdgcn_s_setprio(0);

    __builtin_amdgcn_sched_barrier(0);
    if (t + 2 < NKT) {
      asm volatile("s_waitcnt vmcnt(4)" ::: "memory");  // slot t+1 landed
    } else {
      asm volatile("s_waitcnt vmcnt(0)" ::: "memory");  // tail drain
    }
    __builtin_amdgcn_s_barrier();
    __builtin_amdgcn_sched_barrier(0);
  }
}

// ---------------------------------------------------------------------------
// Fused QKV projection: A=x16 [16512][1024] (exact 129x128 M fit, no tail),
// B=Wqkv16 [3072][1024]. Grid 129*24 flat; nt 0..7 -> q, 8..15 -> k,
// 16..23 -> v (128 cols each).
// ---------------------------------------------------------------------------
__global__ __launch_bounds__(256, 2) void gemm_qkv(
    const u16* __restrict__ A, const u16* __restrict__ B,
    u16* __restrict__ Cq, u16* __restrict__ Ck, u16* __restrict__ Cv)
{
  __shared__ u16 sm[4][8192];          // 64 KB -> 2 WG/CU
  const int tid = threadIdx.x;
  f32x4 acc[4][4];
#pragma unroll
  for (int mi = 0; mi < 4; ++mi)
#pragma unroll
    for (int ni = 0; ni < 4; ++ni)
      acc[mi][ni] = (f32x4){0.f, 0.f, 0.f, 0.f};

  const int wg = xcd_swz(blockIdx.x, 129 * 24);
  const int nt = wg % 24, mt = wg / 24;   // nt fastest: A-tile reuse per XCD
  const int m0 = mt * 128, n0 = nt * 128;

  gemm_pipe_sq(A, B, m0, n0, tid, sm, acc);

  u16* C = nt < 8 ? Cq : (nt < 16 ? Ck : Cv);
  const int c0 = (nt & 7) * 128;
  const int lane = tid & 63, w = tid >> 6;
  const int qd = lane >> 4, l15 = lane & 15;
  const int wm = (w >> 1) * 64, wn = (w & 1) * 64;
#pragma unroll
  for (int mi = 0; mi < 4; ++mi)
#pragma unroll
    for (int ni = 0; ni < 4; ++ni) {
      const int row0 = m0 + wm + mi * 16 + qd * 4;
      const int col  = c0 + wn + ni * 16 + l15;
#pragma unroll
      for (int r = 0; r < 4; ++r)
        C[(size_t)(row0 + r) * DIMSZ + col] = f2bf(acc[mi][ni][r]);
    }
}

// ---------------------------------------------------------------------------
// Output projection: A=ao bf16, B=Wo16 bf16, C=f32 d_out, +bias.
// Grid 129*8 (exact fit both dims), 2 WG/CU.
// ---------------------------------------------------------------------------
__global__ __launch_bounds__(256, 2) void gemm_out(
    const u16* __restrict__ A, const u16* __restrict__ B,
    float* __restrict__ C, const float* __restrict__ bias)
{
  __shared__ u16 sm[4][8192];
  const int tid = threadIdx.x;
  f32x4 acc[4][4];
#pragma unroll
  for (int mi = 0; mi < 4; ++mi)
#pragma unroll
    for (int ni = 0; ni < 4; ++ni)
      acc[mi][ni] = (f32x4){0.f, 0.f, 0.f, 0.f};

  const int wg = xcd_swz(blockIdx.x, 129 * 8);
  const int nt = wg & 7, mt = wg >> 3;
  const int m0 = mt * 128, n0 = nt * 128;

  gemm_pipe_sq(A, B, m0, n0, tid, sm, acc);

  const int lane = tid & 63, w = tid >> 6;
  const int qd = lane >> 4, l15 = lane & 15;
  const int wm = (w >> 1) * 64, wn = (w & 1) * 64;
#pragma unroll
  for (int mi = 0; mi < 4; ++mi)
#pragma unroll
    for (int ni = 0; ni < 4; ++ni) {
      const int row0 = m0 + wm + mi * 16 + qd * 4;
      const int col  = n0 + wn + ni * 16 + l15;
      float badd = bias[col];
#pragma unroll
      for (int r = 0; r < 4; ++r)
        C[(size_t)(row0 + r) * DIMSZ + col] = acc[mi][ni][r] + badd;
    }
}

// ---------------------------------------------------------------------------
// Global attention among the 32 block-leader tokens, per (b,h). One wave/WG.
// ---------------------------------------------------------------------------
__global__ __launch_bounds__(64) void global_attn(
    const u16* __restrict__ q, const u16* __restrict__ k,
    const u16* __restrict__ v, float* __restrict__ g)
{
  __shared__ float sQ[NBLK * 64];
  __shared__ float sKT[64 * NBLK];
  __shared__ float sV[NBLK * 64];
  __shared__ float sp[NBLK];
  const int b = blockIdx.x >> 4, h = blockIdx.x & 15;
  const int lane = threadIdx.x;

  for (int idx = lane; idx < NBLK * 64; idx += 64) {
    int j = idx >> 6, d = idx & 63;
    size_t off = ((size_t)(b * NTOK + j * BLKSZ)) * DIMSZ + h * 64 + d;
    sQ[idx] = bf2f(q[off]);
    sKT[d * NBLK + j] = bf2f(k[off]);
    sV[idx] = bf2f(v[off]);
  }
  __syncthreads();

  for (int i = 0; i < NBLK; ++i) {
    float s = -3.0e38f;
    if (lane < 32) {
      float acc = 0.f;
      for (int d = 0; d < 64; ++d) acc += sQ[i * 64 + d] * sKT[d * NBLK + lane];
      s = acc * 0.125f;
    }
    float m = s;
    for (int t = 1; t < 64; t <<= 1) m = fmaxf(m, __shfl_xor(m, t));
    float e = (lane < 32) ? __expf(s - m) : 0.f;
    float sum = e;
    for (int t = 1; t < 64; t <<= 1) sum += __shfl_xor(sum, t);
    if (lane < 32) sp[lane] = e / sum;
    __syncthreads();
    float acc = 0.f;
    for (int jj = 0; jj < NBLK; ++jj) acc += sp[jj] * sV[jj * 64 + lane];
    g[(((size_t)b * NBLK + i) * HEADS + h) * 64 + lane] = acc;
    __syncthreads();
  }
}

// ---------------------------------------------------------------------------
// MFMA block-local attention, 512 threads (8 waves) per (b, blk, h).
// LDS: sS 144xSSTR (43.8 KB), sKV union (20.7 KB) -> 64.5 KB, 2 WG/CU,
// 16 waves/CU. Strides 152/72 cut 4-16-way LDS bank aliasing to <=2-way.
// Phase-1 tiles are CONTIGUOUS per wave (10-11 each) so the wave's q
// fragments are loaded ~2x instead of ~10x (global-traffic + latency cut).
// Writes ao IN PLACE over q (disjoint WG slices; q reads precede stores).
// ---------------------------------------------------------------------------
__global__ __launch_bounds__(512) void block_attn(
    const u16* q, const u16* __restrict__ k,
    const u16* __restrict__ v, const float* __restrict__ g,
    u16* ao)
{
  __shared__ u16 sS[144 * SSTR];    // scores then P (bf16)
  __shared__ u16 sKV[144 * KSTR];   // phase1: K [key][d] (KSTR); phase3: V^T [dv][key] (SSTR)
  const int b = blockIdx.x, blk = blockIdx.y, h = blockIdx.z;
  const int tid = threadIdx.x, lane = tid & 63, w = tid >> 6;
  const int qd = lane >> 4, l15 = lane & 15;
  const int h64 = h * 64;
  const size_t row_base = (size_t)b * NTOK + (size_t)blk * BLKSZ;
  const f32x4 zero4 = {0.f, 0.f, 0.f, 0.f};

  // ---- K tile [key][d], rows 129..143 zeroed ----
  {
    const u16x8 zero8 = {0, 0, 0, 0, 0, 0, 0, 0};
    for (int c = tid; c < 144 * 8; c += 512) {
      int row = c >> 3, cc = c & 7;
      u16x8 val = zero8;
      if (row < BLKSZ)
        val = *(const u16x8*)(k + (row_base + row) * DIMSZ + h64 + cc * 8);
      *(u16x8*)&sKV[row * KSTR + cc * 8] = val;
    }
  }
  __syncthreads();

  // ---- phase 1: S = 0.125 * Q K^T; 81 tiles as contiguous per-wave runs ----
  {
    const int tbeg = w * 10;
    const int tend = (w == 7) ? 81 : tbeg + 10;
    int cur_mt = -1;
    bf16x8 qf0, qf1;
    for (int t = tbeg; t < tend; ++t) {
      int mt = t / 9, nt = t - mt * 9;
      if (mt != cur_mt) {
        cur_mt = mt;
        int qrow = mt * 16 + l15;
        if (qrow > 128) qrow = 128;    // clamp: keep reads in-bounds
        const u16* qp = q + (row_base + qrow) * DIMSZ + h64;
        qf0 = *(const bf16x8*)(qp + qd * 8);
        qf1 = *(const bf16x8*)(qp + 32 + qd * 8);
      }
      bf16x8 kf0 = *(const bf16x8*)&sKV[(nt * 16 + l15) * KSTR + qd * 8];
      bf16x8 kf1 = *(const bf16x8*)&sKV[(nt * 16 + l15) * KSTR + 32 + qd * 8];
      f32x4 c = zero4;
      c = MFMA(qf0, kf0, c, 0, 0, 0);
      c = MFMA(qf1, kf1, c, 0, 0, 0);
      int r0 = mt * 16 + qd * 4, col = nt * 16 + l15;
#pragma unroll
      for (int r = 0; r < 4; ++r)
        sS[(r0 + r) * SSTR + col] = f2bf(c[r] * 0.125f);
    }
  }
  __syncthreads();

  // ---- V^T [dv][key] stride SSTR into sKV (K tile dead) ----
  for (int c = tid; c < BLKSZ * 8; c += 512) {
    int row = c >> 3, cc = c & 7;      // row = key index
    u16x8 val = *(const u16x8*)(v + (row_base + row) * DIMSZ + h64 + cc * 8);
#pragma unroll
    for (int jj = 0; jj < 8; ++jj)
      sKV[(cc * 8 + jj) * SSTR + row] = val[jj];
  }

  // ---- softmax over 129 keys (rows over 8 waves) ----
  for (int row = w; row < BLKSZ; row += 8) {
    float x1 = bf2f(sS[row * SSTR + lane]);
    float x2 = bf2f(sS[row * SSTR + 64 + lane]);
    float x3 = (lane == 0) ? bf2f(sS[row * SSTR + 128]) : -3.0e38f;
    float m = fmaxf(fmaxf(x1, x2), x3);
    for (int t = 1; t < 64; t <<= 1) m = fmaxf(m, __shfl_xor(m, t));
    float e1 = __expf(x1 - m), e2 = __expf(x2 - m);
    float e3 = (lane == 0) ? __expf(x3 - m) : 0.f;
    float s = e1 + e2 + e3;
    for (int t = 1; t < 64; t <<= 1) s += __shfl_xor(s, t);
    float inv = 1.f / s;
    sS[row * SSTR + lane] = f2bf(e1 * inv);
    sS[row * SSTR + 64 + lane] = f2bf(e2 * inv);
    if (lane == 0) sS[row * SSTR + 128] = f2bf(e3 * inv);
  }
  __syncthreads();

  // ---- phase 3: out = P V (keys 0..127 MFMA + rank-1 key 128) ----
  for (int t = w; t < 36; t += 8) {
    int mt = t >> 2, nt = t & 3;
    f32x4 c = zero4;
#pragma unroll
    for (int kk = 0; kk < 128; kk += 32) {
      bf16x8 pf = *(const bf16x8*)&sS[(mt * 16 + l15) * SSTR + kk + qd * 8];
      bf16x8 vf = *(const bf16x8*)&sKV[(nt * 16 + l15) * SSTR + kk + qd * 8];
      c = MFMA(pf, vf, c, 0, 0, 0);
    }
    int dv = nt * 16 + l15;
    float v128 = bf2f(sKV[dv * SSTR + 128]);
    int r0 = mt * 16 + qd * 4;
#pragma unroll
    for (int r = 0; r < 4; ++r) {
      int row = r0 + r;
      if (row < BLKSZ) {
        float p128 = bf2f(sS[row * SSTR + 128]);
        float val = c[r] + p128 * v128;
        if (row == 0)
          val += g[(((size_t)b * NBLK + blk) * HEADS + h) * 64 + dv];
        ao[(row_base + row) * DIMSZ + h64 + dv] = f2bf(val);
      }
    }
  }
}

// ---------------------------------------------------------------------------
extern "C" void kernel_launch(void* const* d_in, const int* in_sizes, int n_in,
                              void* d_out, int out_size, void* d_ws, size_t ws_size,
                              hipStream_t stream) {
  // Inputs f32; OUTPUT f32 (round-8 verified).
  const float* x  = (const float*)d_in[0];
  const float* Wq = (const float*)d_in[1];
  const float* Wk = (const float*)d_in[2];
  const float* Wv = (const float*)d_in[3];
  const float* Wo = (const float*)d_in[4];
  const float* bo = (const float*)d_in[5];
  float* out = (float*)d_out;

  // Scratch:
  //   d_out (67.6 MB) during attention: [k bf16 33.8][v bf16 33.8]
  //   d_ws (74.6 MB peak):
  //     [0,1MB) g | [1,+33.8) qb (ao in-place) | [+33.8) x16 | [+6MB) Wqkv16
  //   Wo16 reuses the x16 region (cast launched after gemm_qkv, stream-ordered).
  char* ws = (char*)d_ws;
  const size_t xb = (size_t)MROWS * DIMSZ * sizeof(u16);   // 33.8 MB
  float* gb     = (float*)ws;
  u16*   qb     = (u16*)(ws + (1u << 20));
  u16*   x16    = (u16*)(ws + (1u << 20) + xb);
  u16*   Wqkv16 = (u16*)(ws + (1u << 20) + 2 * xb);
  u16*   Wo16   = x16;                     // reused after gemm_qkv
  u16*   kb     = (u16*)d_out;
  u16*   vb     = (u16*)d_out + (size_t)MROWS * DIMSZ;

  const int nx = MROWS * DIMSZ;
  const int nw = DIMSZ * DIMSZ;
  cast_f32_bf16<<<nx / 1024, 256, 0, stream>>>(x,  x16, nx);
  cast_f32_bf16<<<nw / 1024, 256, 0, stream>>>(Wq, Wqkv16,          nw);
  cast_f32_bf16<<<nw / 1024, 256, 0, stream>>>(Wk, Wqkv16 + nw,     nw);
  cast_f32_bf16<<<nw / 1024, 256, 0, stream>>>(Wv, Wqkv16 + 2 * nw, nw);

  gemm_qkv<<<dim3(129 * 24), 256, 0, stream>>>(x16, Wqkv16, qb, kb, vb);

  cast_f32_bf16<<<nw / 1024, 256, 0, stream>>>(Wo, Wo16, nw);   // after qkv: x16 dead

  global_attn<<<dim3(BATCH * HEADS), 64, 0, stream>>>(qb, kb, vb, gb);
  block_attn<<<dim3(BATCH, NBLK, HEADS), 512, 0, stream>>>(qb, kb, vb, gb, qb);
  gemm_out<<<dim3(129 * 8), 256, 0, stream>>>(qb, Wo16, out, bo);
}

// Round 5
// 400.139 us; speedup vs baseline: 1.2115x; 1.0809x over previous
//
#include <hip/hip_runtime.h>

typedef unsigned short u16;
typedef __attribute__((ext_vector_type(8))) __bf16 bf16x8;
typedef __attribute__((ext_vector_type(4))) float f32x4;
typedef __attribute__((ext_vector_type(8))) u16 u16x8;
typedef __attribute__((ext_vector_type(4))) u16 u16x4;

#define DIMSZ 1024
#define HEADS 16
#define BLKSZ 129
#define NBLK 32
#define NTOK (BLKSZ * NBLK)      // 4128
#define BATCH 4
#define MROWS (BATCH * NTOK)     // 16512

#define MFMA __builtin_amdgcn_mfma_f32_16x16x32_bf16

#define SSTR 152   // S/P LDS row stride (bf16): 2-way bank alias only (free)
#define KSTR 72    // K tile LDS row stride

#define NKT 32     // K tiles of 32: 1024/32

__device__ __forceinline__ float bf2f(u16 u) {
  return __uint_as_float(((unsigned)u) << 16);
}
__device__ __forceinline__ u16 f2bf(float f) {
  unsigned u = __float_as_uint(f);
  u += 0x7FFFu + ((u >> 16) & 1u);   // round-to-nearest-even
  return (u16)(u >> 16);
}

// async global->LDS, 16B/lane; LDS dest = wave-uniform base + lane*16 (m97)
#define GLD16(ldsp, gp) __builtin_amdgcn_global_load_lds( \
    (const __attribute__((address_space(1))) void*)(gp),   \
    (__attribute__((address_space(3))) void*)(ldsp), 16, 0, 0)

// ---------------------------------------------------------------------------
// f32 -> bf16 cast, 4 elems/thread. n multiple of 1024.
// ---------------------------------------------------------------------------
__global__ __launch_bounds__(256) void cast_f32_bf16(
    const float* __restrict__ in, u16* __restrict__ out, int n)
{
  int i = (blockIdx.x * 256 + threadIdx.x) * 4;
  if (i < n) {
    float4 f = *(const float4*)(in + i);
    u16x4 o = { f2bf(f.x), f2bf(f.y), f2bf(f.z), f2bf(f.w) };
    *(u16x4*)(out + i) = o;
  }
}

// Fused Wq/Wk/Wv cast: out is the contiguous Wqkv16 [3][1024][1024].
__global__ __launch_bounds__(256) void cast_w3(
    const float* __restrict__ a, const float* __restrict__ b,
    const float* __restrict__ c, u16* __restrict__ out)
{
  const int nw = DIMSZ * DIMSZ;
  int i = (blockIdx.x * 256 + threadIdx.x) * 4;
  const float* src = (i < nw) ? a : (i < 2 * nw ? b : c);
  int j = (i < nw) ? i : (i < 2 * nw ? i - nw : i - 2 * nw);
  float4 f = *(const float4*)(src + j);
  u16x4 o = { f2bf(f.x), f2bf(f.y), f2bf(f.z), f2bf(f.w) };
  *(u16x4*)(out + i) = o;
}

// ---------------------------------------------------------------------------
// Bijective XCD-aware block swizzle (m204): contiguous logical chunk per XCD.
// ---------------------------------------------------------------------------
__device__ __forceinline__ int xcd_swz(int bid, int nwg) {
  const int xcd = bid & 7, l = bid >> 3;
  const int q = nwg >> 3, r = nwg & 7;
  return (xcd < r ? xcd * (q + 1) : r * (q + 1) + (xcd - r) * q) + l;
}

// ---------------------------------------------------------------------------
// Stage one BK=32 slot (A 128x32 + B 128x32 = 16 KB) with 256 threads:
// 4 x global_load_lds dwordx4 per thread. LDS dest linear (lane*16 rule);
// source cols pre-swizzled (chunk ^= (row>>1)&3) so the swizzled ds_read is
// bank-uniform (rule #21). Zero LDS bank conflicts verified on HW (r2-r4).
// ---------------------------------------------------------------------------
__device__ __forceinline__ void stage_sq(u16* slot, const u16* gA,
                                         const u16* gB, int tid) {
  GLD16(slot + tid * 8, gA);                      // A rows 0..63
  GLD16(slot + 2048 + tid * 8, gA + 64 * DIMSZ);  // A rows 64..127
  GLD16(slot + 4096 + tid * 8, gB);               // B rows 0..63
  GLD16(slot + 6144 + tid * 8, gB + 64 * DIMSZ);  // B rows 64..127
}

// ---------------------------------------------------------------------------
// 128x128 pipelined GEMM mainloop: BK=32, 256 threads = 4 waves (2M x 2N),
// wave tile 64x64 (acc[4][4]). 3-slot LDS ring (48 KB) -> 3 WG/CU =
// 12 waves/CU of UNSYNCHRONIZED work: one WG's LDS-read/stage burst overlaps
// the other WGs' MFMA clusters (TLP, no intra-WG sync surgery).
// Rotating-pointer ring (race-verified r3): slot staged at step t is the
// slot read at step t-1, whose reads completed before t-1's end barrier.
// Counted vmcnt(4): slot t+1's 4 loads retire at step t's end; slot t+2's
// stay in flight across the barrier (T4, never drain to 0 mid-loop).
// ---------------------------------------------------------------------------
__device__ __forceinline__ void gemm_pipe_sq(
    const u16* __restrict__ A, const u16* __restrict__ Bm,
    int m0, int n0, int tid, u16 (*sm)[8192], f32x4 (*acc)[4])
{
  const int lane = tid & 63, w = tid >> 6;
  const int qd = lane >> 4, l15 = lane & 15;
  const int wm = (w >> 1) * 64, wn = (w & 1) * 64;
  // read-side swizzle: chunk qd ^ ((row>>1)&3); lane-constant (rows 16-aligned)
  const int qdsw = (qd ^ ((l15 >> 1) & 3)) * 8;

  const int srow = tid >> 2;                      // 0..63
  const int schk = (tid & 3) ^ ((tid >> 3) & 3);  // source chunk swizzle
  const u16* gA = A + (size_t)(m0 + srow) * DIMSZ + schk * 8;
  const u16* gB = Bm + (size_t)(n0 + srow) * DIMSZ + schk * 8;

  u16 *p0 = sm[0], *p1 = sm[1], *p2 = sm[2];

  // prologue: stage slots 0,1; land slot 0, keep slot 1's 4 loads in flight
  stage_sq(p0, gA, gB, tid);
  stage_sq(p1, gA + 32, gB + 32, tid);
  asm volatile("s_waitcnt vmcnt(4)" ::: "memory");
  __builtin_amdgcn_s_barrier();
  __builtin_amdgcn_sched_barrier(0);

  for (int t = 0; t < NKT; ++t) {
    if (t + 2 < NKT)
      stage_sq(p2, gA + (t + 2) * 32, gB + (t + 2) * 32, tid);

    bf16x8 af[4], bv[4];
#pragma unroll
    for (int mi = 0; mi < 4; ++mi)
      af[mi] = *(const bf16x8*)&p0[(wm + mi * 16 + l15) * 32 + qdsw];
#pragma unroll
    for (int ni = 0; ni < 4; ++ni)
      bv[ni] = *(const bf16x8*)&p0[4096 + (wn + ni * 16 + l15) * 32 + qdsw];

    __builtin_amdgcn_s_setprio(1);
#pragma unroll
    for (int mi = 0; mi < 4; ++mi)
#pragma unroll
      for (int ni = 0; ni < 4; ++ni)
        acc[mi][ni] = MFMA(af[mi], bv[ni], acc[mi][ni], 0, 0, 0);
    __builtin_amdgcn_s_setprio(0);

    __builtin_amdgcn_sched_barrier(0);
    if (t + 2 < NKT) {
      asm volatile("s_waitcnt vmcnt(4)" ::: "memory");  // slot t+1 landed
    } else {
      asm volatile("s_waitcnt vmcnt(0)" ::: "memory");  // tail drain
    }
    __builtin_amdgcn_s_barrier();
    __builtin_amdgcn_sched_barrier(0);

    u16* tmp = p0; p0 = p1; p1 = p2; p2 = tmp;   // rotate ring
  }
}

// ---------------------------------------------------------------------------
// Fused QKV projection: A=x16 [16512][1024] (exact 129x128 M fit, no tail),
// B=Wqkv16 [3072][1024]. Grid 129*24 flat; nt 0..7 -> q, 8..15 -> k,
// 16..23 -> v (128 cols each). 3 WG/CU.
// ---------------------------------------------------------------------------
__global__ __launch_bounds__(256, 3) void gemm_qkv(
    const u16* __restrict__ A, const u16* __restrict__ B,
    u16* __restrict__ Cq, u16* __restrict__ Ck, u16* __restrict__ Cv)
{
  __shared__ u16 sm[3][8192];          // 48 KB -> 3 WG/CU
  const int tid = threadIdx.x;
  f32x4 acc[4][4];
#pragma unroll
  for (int mi = 0; mi < 4; ++mi)
#pragma unroll
    for (int ni = 0; ni < 4; ++ni)
      acc[mi][ni] = (f32x4){0.f, 0.f, 0.f, 0.f};

  const int wg = xcd_swz(blockIdx.x, 129 * 24);
  const int nt = wg % 24, mt = wg / 24;   // nt fastest: A-tile reuse per XCD
  const int m0 = mt * 128, n0 = nt * 128;

  gemm_pipe_sq(A, B, m0, n0, tid, sm, acc);

  u16* C = nt < 8 ? Cq : (nt < 16 ? Ck : Cv);
  const int c0 = (nt & 7) * 128;
  const int lane = tid & 63, w = tid >> 6;
  const int qd = lane >> 4, l15 = lane & 15;
  const int wm = (w >> 1) * 64, wn = (w & 1) * 64;
#pragma unroll
  for (int mi = 0; mi < 4; ++mi)
#pragma unroll
    for (int ni = 0; ni < 4; ++ni) {
      const int row0 = m0 + wm + mi * 16 + qd * 4;
      const int col  = c0 + wn + ni * 16 + l15;
#pragma unroll
      for (int r = 0; r < 4; ++r)
        C[(size_t)(row0 + r) * DIMSZ + col] = f2bf(acc[mi][ni][r]);
    }
}

// ---------------------------------------------------------------------------
// Output projection: A=ao bf16, B=Wo16 bf16, C=f32 d_out, +bias.
// Grid 129*8 (exact fit both dims), 3 WG/CU.
// ---------------------------------------------------------------------------
__global__ __launch_bounds__(256, 3) void gemm_out(
    const u16* __restrict__ A, const u16* __restrict__ B,
    float* __restrict__ C, const float* __restrict__ bias)
{
  __shared__ u16 sm[3][8192];
  const int tid = threadIdx.x;
  f32x4 acc[4][4];
#pragma unroll
  for (int mi = 0; mi < 4; ++mi)
#pragma unroll
    for (int ni = 0; ni < 4; ++ni)
      acc[mi][ni] = (f32x4){0.f, 0.f, 0.f, 0.f};

  const int wg = xcd_swz(blockIdx.x, 129 * 8);
  const int nt = wg & 7, mt = wg >> 3;
  const int m0 = mt * 128, n0 = nt * 128;

  gemm_pipe_sq(A, B, m0, n0, tid, sm, acc);

  const int lane = tid & 63, w = tid >> 6;
  const int qd = lane >> 4, l15 = lane & 15;
  const int wm = (w >> 1) * 64, wn = (w & 1) * 64;
#pragma unroll
  for (int mi = 0; mi < 4; ++mi)
#pragma unroll
    for (int ni = 0; ni < 4; ++ni) {
      const int row0 = m0 + wm + mi * 16 + qd * 4;
      const int col  = n0 + wn + ni * 16 + l15;
      float badd = bias[col];
#pragma unroll
      for (int r = 0; r < 4; ++r)
        C[(size_t)(row0 + r) * DIMSZ + col] = acc[mi][ni][r] + badd;
    }
}

// ---------------------------------------------------------------------------
// Global attention among the 32 block-leader tokens, per (b,h).
// 256 threads = 4 waves; wave w owns leader-rows i = w, w+4, ... (8 each).
// Per-wave sp buffer -> ZERO in-loop __syncthreads (waves fully independent
// after the staging barrier). Per-i math identical to the 1-wave version.
// ---------------------------------------------------------------------------
__global__ __launch_bounds__(256) void global_attn(
    const u16* __restrict__ q, const u16* __restrict__ k,
    const u16* __restrict__ v, float* __restrict__ g)
{
  __shared__ float sQ[NBLK * 64];
  __shared__ float sKT[64 * NBLK];
  __shared__ float sV[NBLK * 64];
  __shared__ float sp[4][NBLK];
  const int b = blockIdx.x >> 4, h = blockIdx.x & 15;
  const int tid = threadIdx.x, lane = tid & 63, w = tid >> 6;

  for (int idx = tid; idx < NBLK * 64; idx += 256) {
    int j = idx >> 6, d = idx & 63;
    size_t off = ((size_t)(b * NTOK + j * BLKSZ)) * DIMSZ + h * 64 + d;
    sQ[idx] = bf2f(q[off]);
    sKT[d * NBLK + j] = bf2f(k[off]);
    sV[idx] = bf2f(v[off]);
  }
  __syncthreads();

  for (int i = w; i < NBLK; i += 4) {
    float s = -3.0e38f;
    if (lane < 32) {
      float acc = 0.f;
      for (int d = 0; d < 64; ++d) acc += sQ[i * 64 + d] * sKT[d * NBLK + lane];
      s = acc * 0.125f;
    }
    float m = s;
    for (int t = 1; t < 64; t <<= 1) m = fmaxf(m, __shfl_xor(m, t));
    float e = (lane < 32) ? __expf(s - m) : 0.f;
    float sum = e;
    for (int t = 1; t < 64; t <<= 1) sum += __shfl_xor(sum, t);
    if (lane < 32) sp[w][lane] = e / sum;
    asm volatile("s_waitcnt lgkmcnt(0)" ::: "memory");  // wave-local LDS RAW
    float acc = 0.f;
    for (int jj = 0; jj < NBLK; ++jj) acc += sp[w][jj] * sV[jj * 64 + lane];
    g[(((size_t)b * NBLK + i) * HEADS + h) * 64 + lane] = acc;
  }
}

// ---------------------------------------------------------------------------
// MFMA block-local attention, 512 threads (8 waves) per (b, blk, h).
// LDS: sS 144xSSTR (43.8 KB), sKV union (20.7 KB) -> 64.5 KB, 2 WG/CU,
// 16 waves/CU. Strides 152/72 cut 4-16-way LDS bank aliasing to <=2-way.
// Phase-1 tiles are CONTIGUOUS per wave (10-11 each) so the wave's q
// fragments are loaded ~2x instead of ~10x (global-traffic + latency cut).
// Writes ao IN PLACE over q (disjoint WG slices; q reads precede stores).
// ---------------------------------------------------------------------------
__global__ __launch_bounds__(512) void block_attn(
    const u16* q, const u16* __restrict__ k,
    const u16* __restrict__ v, const float* __restrict__ g,
    u16* ao)
{
  __shared__ u16 sS[144 * SSTR];    // scores then P (bf16)
  __shared__ u16 sKV[144 * KSTR];   // phase1: K [key][d] (KSTR); phase3: V^T [dv][key] (SSTR)
  const int b = blockIdx.x, blk = blockIdx.y, h = blockIdx.z;
  const int tid = threadIdx.x, lane = tid & 63, w = tid >> 6;
  const int qd = lane >> 4, l15 = lane & 15;
  const int h64 = h * 64;
  const size_t row_base = (size_t)b * NTOK + (size_t)blk * BLKSZ;
  const f32x4 zero4 = {0.f, 0.f, 0.f, 0.f};

  // ---- K tile [key][d], rows 129..143 zeroed ----
  {
    const u16x8 zero8 = {0, 0, 0, 0, 0, 0, 0, 0};
    for (int c = tid; c < 144 * 8; c += 512) {
      int row = c >> 3, cc = c & 7;
      u16x8 val = zero8;
      if (row < BLKSZ)
        val = *(const u16x8*)(k + (row_base + row) * DIMSZ + h64 + cc * 8);
      *(u16x8*)&sKV[row * KSTR + cc * 8] = val;
    }
  }
  __syncthreads();

  // ---- phase 1: S = 0.125 * Q K^T; 81 tiles as contiguous per-wave runs ----
  {
    const int tbeg = w * 10;
    const int tend = (w == 7) ? 81 : tbeg + 10;
    int cur_mt = -1;
    bf16x8 qf0, qf1;
    for (int t = tbeg; t < tend; ++t) {
      int mt = t / 9, nt = t - mt * 9;
      if (mt != cur_mt) {
        cur_mt = mt;
        int qrow = mt * 16 + l15;
        if (qrow > 128) qrow = 128;    // clamp: keep reads in-bounds
        const u16* qp = q + (row_base + qrow) * DIMSZ + h64;
        qf0 = *(const bf16x8*)(qp + qd * 8);
        qf1 = *(const bf16x8*)(qp + 32 + qd * 8);
      }
      bf16x8 kf0 = *(const bf16x8*)&sKV[(nt * 16 + l15) * KSTR + qd * 8];
      bf16x8 kf1 = *(const bf16x8*)&sKV[(nt * 16 + l15) * KSTR + 32 + qd * 8];
      f32x4 c = zero4;
      c = MFMA(qf0, kf0, c, 0, 0, 0);
      c = MFMA(qf1, kf1, c, 0, 0, 0);
      int r0 = mt * 16 + qd * 4, col = nt * 16 + l15;
#pragma unroll
      for (int r = 0; r < 4; ++r)
        sS[(r0 + r) * SSTR + col] = f2bf(c[r] * 0.125f);
    }
  }
  __syncthreads();

  // ---- V^T [dv][key] stride SSTR into sKV (K tile dead) ----
  for (int c = tid; c < BLKSZ * 8; c += 512) {
    int row = c >> 3, cc = c & 7;      // row = key index
    u16x8 val = *(const u16x8*)(v + (row_base + row) * DIMSZ + h64 + cc * 8);
#pragma unroll
    for (int jj = 0; jj < 8; ++jj)
      sKV[(cc * 8 + jj) * SSTR + row] = val[jj];
  }

  // ---- softmax over 129 keys (rows over 8 waves) ----
  for (int row = w; row < BLKSZ; row += 8) {
    float x1 = bf2f(sS[row * SSTR + lane]);
    float x2 = bf2f(sS[row * SSTR + 64 + lane]);
    float x3 = (lane == 0) ? bf2f(sS[row * SSTR + 128]) : -3.0e38f;
    float m = fmaxf(fmaxf(x1, x2), x3);
    for (int t = 1; t < 64; t <<= 1) m = fmaxf(m, __shfl_xor(m, t));
    float e1 = __expf(x1 - m), e2 = __expf(x2 - m);
    float e3 = (lane == 0) ? __expf(x3 - m) : 0.f;
    float s = e1 + e2 + e3;
    for (int t = 1; t < 64; t <<= 1) s += __shfl_xor(s, t);
    float inv = 1.f / s;
    sS[row * SSTR + lane] = f2bf(e1 * inv);
    sS[row * SSTR + 64 + lane] = f2bf(e2 * inv);
    if (lane == 0) sS[row * SSTR + 128] = f2bf(e3 * inv);
  }
  __syncthreads();

  // ---- phase 3: out = P V (keys 0..127 MFMA + rank-1 key 128) ----
  for (int t = w; t < 36; t += 8) {
    int mt = t >> 2, nt = t & 3;
    f32x4 c = zero4;
#pragma unroll
    for (int kk = 0; kk < 128; kk += 32) {
      bf16x8 pf = *(const bf16x8*)&sS[(mt * 16 + l15) * SSTR + kk + qd * 8];
      bf16x8 vf = *(const bf16x8*)&sKV[(nt * 16 + l15) * SSTR + kk + qd * 8];
      c = MFMA(pf, vf, c, 0, 0, 0);
    }
    int dv = nt * 16 + l15;
    float v128 = bf2f(sKV[dv * SSTR + 128]);
    int r0 = mt * 16 + qd * 4;
#pragma unroll
    for (int r = 0; r < 4; ++r) {
      int row = r0 + r;
      if (row < BLKSZ) {
        float p128 = bf2f(sS[row * SSTR + 128]);
        float val = c[r] + p128 * v128;
        if (row == 0)
          val += g[(((size_t)b * NBLK + blk) * HEADS + h) * 64 + dv];
        ao[(row_base + row) * DIMSZ + h64 + dv] = f2bf(val);
      }
    }
  }
}

// ---------------------------------------------------------------------------
extern "C" void kernel_launch(void* const* d_in, const int* in_sizes, int n_in,
                              void* d_out, int out_size, void* d_ws, size_t ws_size,
                              hipStream_t stream) {
  // Inputs f32; OUTPUT f32 (round-8 verified).
  const float* x  = (const float*)d_in[0];
  const float* Wq = (const float*)d_in[1];
  const float* Wk = (const float*)d_in[2];
  const float* Wv = (const float*)d_in[3];
  const float* Wo = (const float*)d_in[4];
  const float* bo = (const float*)d_in[5];
  float* out = (float*)d_out;

  // Scratch:
  //   d_out (67.6 MB) during attention: [k bf16 33.8][v bf16 33.8]
  //   d_ws (74.6 MB peak):
  //     [0,1MB) g | [1,+33.8) qb (ao in-place) | [+33.8) x16 | [+6MB) Wqkv16
  //   Wo16 reuses the x16 region (cast launched after gemm_qkv, stream-ordered).
  char* ws = (char*)d_ws;
  const size_t xb = (size_t)MROWS * DIMSZ * sizeof(u16);   // 33.8 MB
  float* gb     = (float*)ws;
  u16*   qb     = (u16*)(ws + (1u << 20));
  u16*   x16    = (u16*)(ws + (1u << 20) + xb);
  u16*   Wqkv16 = (u16*)(ws + (1u << 20) + 2 * xb);
  u16*   Wo16   = x16;                     // reused after gemm_qkv
  u16*   kb     = (u16*)d_out;
  u16*   vb     = (u16*)d_out + (size_t)MROWS * DIMSZ;

  const int nx = MROWS * DIMSZ;
  const int nw = DIMSZ * DIMSZ;
  cast_f32_bf16<<<nx / 1024, 256, 0, stream>>>(x, x16, nx);
  cast_w3<<<3 * nw / 1024, 256, 0, stream>>>(Wq, Wk, Wv, Wqkv16);

  gemm_qkv<<<dim3(129 * 24), 256, 0, stream>>>(x16, Wqkv16, qb, kb, vb);

  cast_f32_bf16<<<nw / 1024, 256, 0, stream>>>(Wo, Wo16, nw);   // after qkv: x16 dead

  global_attn<<<dim3(BATCH * HEADS), 256, 0, stream>>>(qb, kb, vb, gb);
  block_attn<<<dim3(BATCH, NBLK, HEADS), 512, 0, stream>>>(qb, kb, vb, gb, qb);
  gemm_out<<<dim3(129 * 8), 256, 0, stream>>>(qb, Wo16, out, bo);
}